// Round 4
// baseline (186.931 us; speedup 1.0000x reference)
//
#include <hip/hip_runtime.h>
#include <math.h>

// Problem constants (match reference).
#define BDIM 4096
#define TDIM 2048
#define NBLK 512          // k1 grid: BDIM / RPB  (partial stays [512][2048] = 4 MB; ws < 8.4 MB)
#define RPB  8            // rows per k1 block
#define GROUPS 4          // parallel row-groups per k1 block (4 waves each)

// gamma powers as exact compile-time folded constants
constexpr double gpow(int e) {
    double r = 1.0;
    for (int i = 0; i < e; ++i) r *= 0.99;
    return r;
}

__device__ __forceinline__ float logsig_fast(float x) {
    // log(sigmoid(x)) = min(x,0) - log(1 + exp(-|x|)); HW transcendentals.
    float z = __expf(-fabsf(x));
    return fminf(x, 0.0f) - __logf(1.0f + z);
}

__device__ __forceinline__ float clip5(float x) {
    return fminf(fmaxf(x, -5.0f), 5.0f);
}

// ---------------------------------------------------------------------------
// K1: per-row reverse discounted scan (c[t] = wr[t] + g*c[t+1]); writes cum
// and per-block column partials. 1024 threads = 4 independent 256-thread scan
// groups, each handling one row at a time (2 rows total per group).
// Grid 512 x 1024thr = 2 blocks/CU x 16 waves -> 32 waves/CU (vs 27% before).
// Blocks 0/1 zero colsum/obj (replaces memsets).
// ---------------------------------------------------------------------------
__global__ __launch_bounds__(1024, 8) void k1_scan(
    const float* __restrict__ logits,
    const float* __restrict__ weight,
    const float* __restrict__ baselines,
    float* __restrict__ cum_out,
    float* __restrict__ partial,
    float* __restrict__ colsum,
    float* __restrict__ obj)
{
    const int tid    = threadIdx.x;
    const int group  = tid >> 8;         // 0..3 (row-group, 4 waves each)
    const int gt     = tid & 255;        // thread index within group
    const int lane   = tid & 63;         // lane within wave (group-aligned)
    const int wavein = (tid >> 6) & 3;   // wave within group
    const int t0     = gt * 8;           // 8 contiguous columns per thread

    // in-kernel zeroing (k2/k3 are stream-ordered after k1)
    if (blockIdx.x == 0 && tid < 256) {
        *reinterpret_cast<float4*>(colsum + t0)     = make_float4(0.f, 0.f, 0.f, 0.f);
        *reinterpret_cast<float4*>(colsum + t0 + 4) = make_float4(0.f, 0.f, 0.f, 0.f);
    }
    if (blockIdx.x == 1 && tid < 256) {
        *reinterpret_cast<float4*>(obj + t0)     = make_float4(0.f, 0.f, 0.f, 0.f);
        *reinterpret_cast<float4*>(obj + t0 + 4) = make_float4(0.f, 0.f, 0.f, 0.f);
    }

    const float G    = 0.99f;
    const float G512 = (float)gpow(512);
    const float LOG2G = -0.014499569695115089f;  // log2(0.99)
    const float gk[8] = {(float)gpow(8), (float)gpow(7), (float)gpow(6), (float)gpow(5),
                         (float)gpow(4), (float)gpow(3), (float)gpow(2), (float)gpow(1)};
    // shuffle-scan factors gamma^(8*2^s) as compile-time constants
    const float fs[6] = {(float)gpow(8),  (float)gpow(16), (float)gpow(32),
                         (float)gpow(64), (float)gpow(128), (float)gpow(256)};
    const float lane_pow = exp2f((float)((64 - lane) * 8) * LOG2G);

    __shared__ float wsum[GROUPS][2][4];
    __shared__ float merge[3][256][8];   // groups 1..3 dump colacc for group 0

    float colacc[8];
#pragma unroll
    for (int k = 0; k < 8; ++k) colacc[k] = 0.0f;

    const int row0 = blockIdx.x * RPB;
    // this group's rows: row0+group, row0+group+4
    size_t base = (size_t)(row0 + group) * TDIM + t0;

    // preload this group's first row
    float4 x0 = *reinterpret_cast<const float4*>(logits + base);
    float4 x1 = *reinterpret_cast<const float4*>(logits + base + 4);
    float4 w0 = *reinterpret_cast<const float4*>(weight + base);
    float4 w1 = *reinterpret_cast<const float4*>(weight + base + 4);
    float4 b0 = *reinterpret_cast<const float4*>(baselines + base);
    float4 b1 = *reinterpret_cast<const float4*>(baselines + base + 4);

#pragma unroll
    for (int i = 0; i < 2; ++i) {
        const size_t nbase = base + (size_t)GROUPS * TDIM;
        const bool has_next = (i == 0);

        float wr[8];
        wr[0] = w0.x * logsig_fast(x0.x); wr[1] = w0.y * logsig_fast(x0.y);
        wr[2] = w0.z * logsig_fast(x0.z); wr[3] = w0.w * logsig_fast(x0.w);
        wr[4] = w1.x * logsig_fast(x1.x); wr[5] = w1.y * logsig_fast(x1.y);
        wr[6] = w1.z * logsig_fast(x1.z); wr[7] = w1.w * logsig_fast(x1.w);

        // prefetch next row: latency hides under the scan chain below
        float4 nx0, nx1, nw0, nw1, nb0, nb1;
        if (has_next) {
            nx0 = *reinterpret_cast<const float4*>(logits + nbase);
            nx1 = *reinterpret_cast<const float4*>(logits + nbase + 4);
            nw0 = *reinterpret_cast<const float4*>(weight + nbase);
            nw1 = *reinterpret_cast<const float4*>(weight + nbase + 4);
            nb0 = *reinterpret_cast<const float4*>(baselines + nbase);
            nb1 = *reinterpret_cast<const float4*>(baselines + nbase + 4);
        }

        // local suffix scan: loc[k] = sum_{s>=k} g^(s-k) wr[s]
        float loc[8];
        loc[7] = wr[7];
#pragma unroll
        for (int k = 6; k >= 0; --k) loc[k] = fmaf(G, loc[k + 1], wr[k]);

        // wave-level weighted suffix scan over per-thread totals
        float v = loc[0];
#pragma unroll
        for (int s = 0; s < 6; ++s) {
            const int o = 1 << s;
            float up = __shfl_down(v, (unsigned)o, 64);
            if (lane + o < 64) v = fmaf(fs[s], up, v);
        }

        // cross-wave carry via per-group LDS — ONE barrier per iteration
        if (lane == 0) wsum[group][i][wavein] = v;
        __syncthreads();
        const float W1 = wsum[group][i][1], W2 = wsum[group][i][2], W3 = wsum[group][i][3];
        const float FC3 = W3;
        const float FC2 = fmaf(G512, FC3, W2);
        const float FC1 = fmaf(G512, FC2, W1);
        const float carry = (wavein == 0) ? FC1 : (wavein == 1) ? FC2 : (wavein == 2) ? FC3 : 0.0f;

        const float vfull = fmaf(lane_pow, carry, v);
        const float vn = __shfl_down(vfull, 1, 64);
        const float tail = (lane == 63) ? carry : vn;

        float c[8];
#pragma unroll
        for (int k = 0; k < 8; ++k) c[k] = fmaf(gk[k], tail, loc[k]);

        *reinterpret_cast<float4*>(cum_out + base)     = make_float4(c[0], c[1], c[2], c[3]);
        *reinterpret_cast<float4*>(cum_out + base + 4) = make_float4(c[4], c[5], c[6], c[7]);

        colacc[0] += c[0] - b0.x; colacc[1] += c[1] - b0.y;
        colacc[2] += c[2] - b0.z; colacc[3] += c[3] - b0.w;
        colacc[4] += c[4] - b1.x; colacc[5] += c[5] - b1.y;
        colacc[6] += c[6] - b1.z; colacc[7] += c[7] - b1.w;

        base = nbase;
        if (has_next) {
            x0 = nx0; x1 = nx1; w0 = nw0; w1 = nw1; b0 = nb0; b1 = nb1;
        }
    }

    // merge the 4 groups' column partials (same columns across groups)
    if (group != 0) {
        *reinterpret_cast<float4*>(&merge[group - 1][gt][0]) =
            make_float4(colacc[0], colacc[1], colacc[2], colacc[3]);
        *reinterpret_cast<float4*>(&merge[group - 1][gt][4]) =
            make_float4(colacc[4], colacc[5], colacc[6], colacc[7]);
    }
    __syncthreads();
    if (group == 0) {
#pragma unroll
        for (int g = 0; g < 3; ++g) {
            float4 m0 = *reinterpret_cast<const float4*>(&merge[g][gt][0]);
            float4 m1 = *reinterpret_cast<const float4*>(&merge[g][gt][4]);
            colacc[0] += m0.x; colacc[1] += m0.y; colacc[2] += m0.z; colacc[3] += m0.w;
            colacc[4] += m1.x; colacc[5] += m1.y; colacc[6] += m1.z; colacc[7] += m1.w;
        }
        const size_t pbase = (size_t)blockIdx.x * TDIM + t0;
        *reinterpret_cast<float4*>(partial + pbase)     = make_float4(colacc[0], colacc[1], colacc[2], colacc[3]);
        *reinterpret_cast<float4*>(partial + pbase + 4) = make_float4(colacc[4], colacc[5], colacc[6], colacc[7]);
    }
}

// ---------------------------------------------------------------------------
// K2: colsum[col] = sum over 512 partial rows (32 slices x 16 rows).
// ---------------------------------------------------------------------------
__global__ __launch_bounds__(256) void k2_colsum(
    const float* __restrict__ partial, float* __restrict__ colsum)
{
    const int gid = blockIdx.x * 256 + threadIdx.x;   // 0..65535
    const int col = gid & (TDIM - 1);
    const int slc = gid >> 11;                        // 0..31
    const float* p = partial + (size_t)slc * 16 * TDIM + col;
    float s = 0.0f;
#pragma unroll
    for (int i = 0; i < 16; ++i) s += p[(size_t)i * TDIM];
    atomicAdd(colsum + col, s);
}

// ---------------------------------------------------------------------------
// K3: obj[t] = sum_b clip(cum - baseline - mean, +-5) * log_probs.
// 16 rows/thread, float4 cols, grid (2,256) = 512 blocks = 25% occupancy.
// ---------------------------------------------------------------------------
#define K3_ROWS 16
__global__ __launch_bounds__(256) void k3_obj(
    const float* __restrict__ cum,
    const float* __restrict__ baselines,
    const float* __restrict__ lp,
    const float* __restrict__ colsum,
    float* __restrict__ obj)
{
    const int c4 = (blockIdx.x * 256 + threadIdx.x) * 4;   // column group
    const int r0 = blockIdx.y * K3_ROWS;
    const float inv = 1.0f / (float)BDIM;
    float4 ms = *reinterpret_cast<const float4*>(colsum + c4);
    const float m0 = ms.x * inv, m1 = ms.y * inv, m2 = ms.z * inv, m3 = ms.w * inv;

    float a0 = 0.0f, a1 = 0.0f, a2 = 0.0f, a3 = 0.0f;
    size_t idx = (size_t)r0 * TDIM + c4;
#pragma unroll 4
    for (int r = 0; r < K3_ROWS; ++r, idx += TDIM) {
        float4 c = *reinterpret_cast<const float4*>(cum + idx);
        float4 b = *reinterpret_cast<const float4*>(baselines + idx);
        float4 l = *reinterpret_cast<const float4*>(lp + idx);
        a0 = fmaf(clip5(c.x - b.x - m0), l.x, a0);
        a1 = fmaf(clip5(c.y - b.y - m1), l.y, a1);
        a2 = fmaf(clip5(c.z - b.z - m2), l.z, a2);
        a3 = fmaf(clip5(c.w - b.w - m3), l.w, a3);
    }
    atomicAdd(obj + c4 + 0, a0);
    atomicAdd(obj + c4 + 1, a1);
    atomicAdd(obj + c4 + 2, a2);
    atomicAdd(obj + c4 + 3, a3);
}

extern "C" void kernel_launch(void* const* d_in, const int* in_sizes, int n_in,
                              void* d_out, int out_size, void* d_ws, size_t ws_size,
                              hipStream_t stream) {
    const float* log_probs = (const float*)d_in[0];   // [B,T]
    const float* logits    = (const float*)d_in[1];   // [B,T,1]
    const float* weight    = (const float*)d_in[2];   // [B,T]
    const float* baselines = (const float*)d_in[3];   // [B,T,1]

    float* out = (float*)d_out;
    float* obj = out;            // [T]
    float* cum = out + TDIM;     // [B,T]

    float* partial = (float*)d_ws;                       // NBLK*TDIM floats = 4 MB
    float* colsum  = partial + (size_t)NBLK * TDIM;      // 2048 floats

    k1_scan<<<NBLK, 1024, 0, stream>>>(logits, weight, baselines, cum, partial, colsum, obj);
    k2_colsum<<<256, 256, 0, stream>>>(partial, colsum);
    k3_obj<<<dim3(TDIM / (256 * 4), BDIM / K3_ROWS), 256, 0, stream>>>(
        cum, baselines, log_probs, colsum, obj);
}

// Round 5
// 165.573 us; speedup vs baseline: 1.1290x; 1.1290x over previous
//
#include <hip/hip_runtime.h>
#include <math.h>

// Problem constants (match reference).
#define BDIM 4096
#define TDIM 2048
#define NBLK 512          // k1 grid: BDIM / RPB  (partial stays [512][2048] = 4 MB)
#define RPB  8            // rows per k1 block

// gamma powers as exact compile-time folded constants
constexpr double gpow(int e) {
    double r = 1.0;
    for (int i = 0; i < e; ++i) r *= 0.99;
    return r;
}

__device__ __forceinline__ float logsig_fast(float x) {
    // log(sigmoid(x)) = min(x,0) - log(1 + exp(-|x|)); HW transcendentals.
    float z = __expf(-fabsf(x));
    return fminf(x, 0.0f) - __logf(1.0f + z);
}

__device__ __forceinline__ float clip5(float x) {
    return fminf(fmaxf(x, -5.0f), 5.0f);
}

// ---------------------------------------------------------------------------
// K1: per-row reverse discounted scan (c[t] = wr[t] + g*c[t+1]); writes cum
// and per-block column partials. Proven round-3 shape (256 thr, 512 blocks).
// Blocks 0/1 zero colsum/obj (replaces memsets).
// ---------------------------------------------------------------------------
__global__ __launch_bounds__(256) void k1_scan(
    const float* __restrict__ logits,
    const float* __restrict__ weight,
    const float* __restrict__ baselines,
    float* __restrict__ cum_out,
    float* __restrict__ partial,
    float* __restrict__ colsum,
    float* __restrict__ obj)
{
    const int tid  = threadIdx.x;
    const int lane = tid & 63;
    const int wave = tid >> 6;
    const int t0   = tid * 8;          // 8 contiguous columns per thread

    // in-kernel zeroing (k2/k3/k4 are stream-ordered after k1)
    if (blockIdx.x == 0) {
        *reinterpret_cast<float4*>(colsum + t0)     = make_float4(0.f, 0.f, 0.f, 0.f);
        *reinterpret_cast<float4*>(colsum + t0 + 4) = make_float4(0.f, 0.f, 0.f, 0.f);
    }
    if (blockIdx.x == 1) {
        *reinterpret_cast<float4*>(obj + t0)     = make_float4(0.f, 0.f, 0.f, 0.f);
        *reinterpret_cast<float4*>(obj + t0 + 4) = make_float4(0.f, 0.f, 0.f, 0.f);
    }

    const float G    = 0.99f;
    const float G512 = (float)gpow(512);
    const float LOG2G = -0.014499569695115089f;  // log2(0.99)
    const float gk[8] = {(float)gpow(8), (float)gpow(7), (float)gpow(6), (float)gpow(5),
                         (float)gpow(4), (float)gpow(3), (float)gpow(2), (float)gpow(1)};
    // shuffle-scan factors gamma^(8*2^s) as compile-time constants
    const float fs[6] = {(float)gpow(8),  (float)gpow(16), (float)gpow(32),
                         (float)gpow(64), (float)gpow(128), (float)gpow(256)};
    const float lane_pow = exp2f((float)((64 - lane) * 8) * LOG2G);

    __shared__ float wsum[2][4];

    float colacc[8];
#pragma unroll
    for (int k = 0; k < 8; ++k) colacc[k] = 0.0f;

    const int row0 = blockIdx.x * RPB;
    size_t base = (size_t)row0 * TDIM + t0;

    // preload row 0
    float4 x0 = *reinterpret_cast<const float4*>(logits + base);
    float4 x1 = *reinterpret_cast<const float4*>(logits + base + 4);
    float4 w0 = *reinterpret_cast<const float4*>(weight + base);
    float4 w1 = *reinterpret_cast<const float4*>(weight + base + 4);
    float4 b0 = *reinterpret_cast<const float4*>(baselines + base);
    float4 b1 = *reinterpret_cast<const float4*>(baselines + base + 4);

    for (int r = 0; r < RPB; ++r) {
        const size_t nbase = base + TDIM;
        const bool has_next = (r + 1 < RPB);

        float wr[8];
        wr[0] = w0.x * logsig_fast(x0.x); wr[1] = w0.y * logsig_fast(x0.y);
        wr[2] = w0.z * logsig_fast(x0.z); wr[3] = w0.w * logsig_fast(x0.w);
        wr[4] = w1.x * logsig_fast(x1.x); wr[5] = w1.y * logsig_fast(x1.y);
        wr[6] = w1.z * logsig_fast(x1.z); wr[7] = w1.w * logsig_fast(x1.w);

        // prefetch next row: latency hides under the scan chain below
        float4 nx0, nx1, nw0, nw1, nb0, nb1;
        if (has_next) {
            nx0 = *reinterpret_cast<const float4*>(logits + nbase);
            nx1 = *reinterpret_cast<const float4*>(logits + nbase + 4);
            nw0 = *reinterpret_cast<const float4*>(weight + nbase);
            nw1 = *reinterpret_cast<const float4*>(weight + nbase + 4);
            nb0 = *reinterpret_cast<const float4*>(baselines + nbase);
            nb1 = *reinterpret_cast<const float4*>(baselines + nbase + 4);
        }

        // local suffix scan: loc[k] = sum_{s>=k} g^(s-k) wr[s]
        float loc[8];
        loc[7] = wr[7];
#pragma unroll
        for (int k = 6; k >= 0; --k) loc[k] = fmaf(G, loc[k + 1], wr[k]);

        // wave-level weighted suffix scan over per-thread totals
        float v = loc[0];
#pragma unroll
        for (int s = 0; s < 6; ++s) {
            const int o = 1 << s;
            float up = __shfl_down(v, (unsigned)o, 64);
            if (lane + o < 64) v = fmaf(fs[s], up, v);
        }

        // cross-wave carry via LDS — ONE barrier per row (double-buffered)
        const int buf = r & 1;
        if (lane == 0) wsum[buf][wave] = v;
        __syncthreads();
        const float W1 = wsum[buf][1], W2 = wsum[buf][2], W3 = wsum[buf][3];
        const float FC3 = W3;
        const float FC2 = fmaf(G512, FC3, W2);
        const float FC1 = fmaf(G512, FC2, W1);
        const float carry = (wave == 0) ? FC1 : (wave == 1) ? FC2 : (wave == 2) ? FC3 : 0.0f;

        const float vfull = fmaf(lane_pow, carry, v);
        const float vn = __shfl_down(vfull, 1, 64);
        const float tail = (lane == 63) ? carry : vn;

        float c[8];
#pragma unroll
        for (int k = 0; k < 8; ++k) c[k] = fmaf(gk[k], tail, loc[k]);

        *reinterpret_cast<float4*>(cum_out + base)     = make_float4(c[0], c[1], c[2], c[3]);
        *reinterpret_cast<float4*>(cum_out + base + 4) = make_float4(c[4], c[5], c[6], c[7]);

        colacc[0] += c[0] - b0.x; colacc[1] += c[1] - b0.y;
        colacc[2] += c[2] - b0.z; colacc[3] += c[3] - b0.w;
        colacc[4] += c[4] - b1.x; colacc[5] += c[5] - b1.y;
        colacc[6] += c[6] - b1.z; colacc[7] += c[7] - b1.w;

        base = nbase;
        if (has_next) {
            x0 = nx0; x1 = nx1; w0 = nw0; w1 = nw1; b0 = nb0; b1 = nb1;
        }
    }

    const size_t pbase = (size_t)blockIdx.x * TDIM + t0;
    *reinterpret_cast<float4*>(partial + pbase)     = make_float4(colacc[0], colacc[1], colacc[2], colacc[3]);
    *reinterpret_cast<float4*>(partial + pbase + 4) = make_float4(colacc[4], colacc[5], colacc[6], colacc[7]);
}

// ---------------------------------------------------------------------------
// K2: colsum[col] = sum over 512 partial rows (32 slices x 16 rows).
// ---------------------------------------------------------------------------
__global__ __launch_bounds__(256) void k2_colsum(
    const float* __restrict__ partial, float* __restrict__ colsum)
{
    const int gid = blockIdx.x * 256 + threadIdx.x;   // 0..65535
    const int col = gid & (TDIM - 1);
    const int slc = gid >> 11;                        // 0..31
    const float* p = partial + (size_t)slc * 16 * TDIM + col;
    float s = 0.0f;
#pragma unroll
    for (int i = 0; i < 16; ++i) s += p[(size_t)i * TDIM];
    atomicAdd(colsum + col, s);
}

// ---------------------------------------------------------------------------
// K3: per-y-block objective partials — NO atomics.
// grid (2, 512) = 1024 blocks = 16 waves/CU; 8 rows/thread, float4 cols.
// Writes objpart[yblock][col] into the (reused) partial buffer.
// ---------------------------------------------------------------------------
#define K3_ROWS 8
__global__ __launch_bounds__(256) void k3_part(
    const float* __restrict__ cum,
    const float* __restrict__ baselines,
    const float* __restrict__ lp,
    const float* __restrict__ colsum,
    float* __restrict__ objpart)
{
    const int c4 = (blockIdx.x * 256 + threadIdx.x) * 4;   // column group
    const int yb = blockIdx.y;                             // 0..511
    const int r0 = yb * K3_ROWS;
    const float inv = 1.0f / (float)BDIM;
    float4 ms = *reinterpret_cast<const float4*>(colsum + c4);
    const float m0 = ms.x * inv, m1 = ms.y * inv, m2 = ms.z * inv, m3 = ms.w * inv;

    float a0 = 0.0f, a1 = 0.0f, a2 = 0.0f, a3 = 0.0f;
    size_t idx = (size_t)r0 * TDIM + c4;
#pragma unroll
    for (int r = 0; r < K3_ROWS; ++r, idx += TDIM) {
        float4 c = *reinterpret_cast<const float4*>(cum + idx);
        float4 b = *reinterpret_cast<const float4*>(baselines + idx);
        float4 l = *reinterpret_cast<const float4*>(lp + idx);
        a0 = fmaf(clip5(c.x - b.x - m0), l.x, a0);
        a1 = fmaf(clip5(c.y - b.y - m1), l.y, a1);
        a2 = fmaf(clip5(c.z - b.z - m2), l.z, a2);
        a3 = fmaf(clip5(c.w - b.w - m3), l.w, a3);
    }
    *reinterpret_cast<float4*>(objpart + (size_t)yb * TDIM + c4) =
        make_float4(a0, a1, a2, a3);
}

// ---------------------------------------------------------------------------
// K4: obj[col] = sum over 512 objpart rows (32 slices x 16 rows) — k2 clone.
// ---------------------------------------------------------------------------
__global__ __launch_bounds__(256) void k4_objsum(
    const float* __restrict__ objpart, float* __restrict__ obj)
{
    const int gid = blockIdx.x * 256 + threadIdx.x;   // 0..65535
    const int col = gid & (TDIM - 1);
    const int slc = gid >> 11;                        // 0..31
    const float* p = objpart + (size_t)slc * 16 * TDIM + col;
    float s = 0.0f;
#pragma unroll
    for (int i = 0; i < 16; ++i) s += p[(size_t)i * TDIM];
    atomicAdd(obj + col, s);
}

extern "C" void kernel_launch(void* const* d_in, const int* in_sizes, int n_in,
                              void* d_out, int out_size, void* d_ws, size_t ws_size,
                              hipStream_t stream) {
    const float* log_probs = (const float*)d_in[0];   // [B,T]
    const float* logits    = (const float*)d_in[1];   // [B,T,1]
    const float* weight    = (const float*)d_in[2];   // [B,T]
    const float* baselines = (const float*)d_in[3];   // [B,T,1]

    float* out = (float*)d_out;
    float* obj = out;            // [T]
    float* cum = out + TDIM;     // [B,T]

    float* partial = (float*)d_ws;                       // [512][2048] = 4 MB
    float* colsum  = partial + (size_t)NBLK * TDIM;      // 2048 floats

    // k1 writes partial (colacc) and zeroes colsum/obj.
    k1_scan<<<NBLK, 256, 0, stream>>>(logits, weight, baselines, cum, partial, colsum, obj);
    // k2 consumes partial -> colsum.
    k2_colsum<<<256, 256, 0, stream>>>(partial, colsum);
    // k3 reuses partial as objpart (k2 finished reading it; stream-ordered).
    k3_part<<<dim3(2, 512), 256, 0, stream>>>(cum, baselines, log_probs, colsum, partial);
    // k4 reduces objpart -> obj.
    k4_objsum<<<256, 256, 0, stream>>>(partial, obj);
}